// Round 1
// baseline (1251.832 us; speedup 1.0000x reference)
//
#include <hip/hip_runtime.h>
#include <math.h>

// LSTM fused persistent kernel. B=1024,T=256,D=128,H=64,G=4H=256,O=128. fp32.
// grid 256 blocks x 256 thr; block owns 4 batches for all 256 steps.
// Thread g keeps W_ih[g][:] (128 VGPR) + W_hh[g][:] (64 VGPR) in registers.
// Per step: role1 (thread=gate g): gates[b][g] = bias + x_t[b].W_ih[g] + h[b].W_hh[g]
//           role2 (thread=(b,j)): activations, c/h update; c lives in a register.
constexpr int B = 1024, T = 256, D = 128, H = 64, G = 256, O = 128;
#define BQ 4

__device__ __forceinline__ float sigmoidf_(float x) {
    return 1.0f / (1.0f + __expf(-x));
}
__device__ __forceinline__ float tanhf_(float x) {
    // overflow-safe: e=exp(2|x|) -> inf gives r=1
    float a = fabsf(x);
    float e = __expf(2.0f * a);
    float r = 1.0f - 2.0f / (e + 1.0f);
    return copysignf(r, x);
}

__global__ __launch_bounds__(256, 1)
void lstm_fused(const float* __restrict__ x, const float* __restrict__ Wih,
                const float* __restrict__ Whh, const float* __restrict__ bih,
                const float* __restrict__ bhh, const float* __restrict__ Wo,
                const float* __restrict__ bo, float* __restrict__ out)
{
    __shared__ float xs[2][BQ][D];   // 4 KB, double-buffered x_t slab
    __shared__ float hbuf[BQ][H];    // 1 KB
    __shared__ float gbuf[BQ][G];    // 4 KB gate pre-activations

    const int tid = threadIdx.x;
    const int g   = tid;        // role1: gate row
    const int w   = tid >> 6;   // wave index = role2 batch
    const int j   = tid & 63;   // lane = role2 hidden unit
    const int b0  = blockIdx.x * BQ;

    // --- weights into registers (one-time; L2-amortized across blocks) ---
    float4 wih[D / 4];
    {
        const float4* p = (const float4*)(Wih + (size_t)g * D);
        #pragma unroll
        for (int i = 0; i < D / 4; ++i) wih[i] = p[i];
    }
    float4 whh[H / 4];
    {
        const float4* p = (const float4*)(Whh + (size_t)g * H);
        #pragma unroll
        for (int i = 0; i < H / 4; ++i) whh[i] = p[i];
    }
    const float bias = bih[g] + bhh[g];

    // --- init h=0, stage x[t=0] ---
    const int fi = tid * 2;
    const int bb = fi >> 7;        // which of the 4 batches this thread stages
    const int dd = fi & (D - 1);   // d offset (float2)
    {
        const float* p = x + ((size_t)(b0 + bb) * T + 0) * D + dd;
        *(float2*)&xs[0][bb][dd] = *(const float2*)p;
        hbuf[w][j] = 0.0f;
    }
    __syncthreads();

    float c = 0.0f;
    int cur = 0;

    for (int t = 0; t < T; ++t) {
        // prefetch next step's x slab into registers (hidden behind compute)
        float2 pxv;
        if (t + 1 < T) {
            const float* p = x + ((size_t)(b0 + bb) * T + (t + 1)) * D + dd;
            pxv = *(const float2*)p;
        }

        // ---- role 1: gate pre-activations for 4 batches ----
        float acc[BQ];
        #pragma unroll
        for (int b = 0; b < BQ; ++b) {
            float a = 0.0f;
            const float4* xp = (const float4*)xs[cur][b];
            #pragma unroll
            for (int i = 0; i < D / 4; ++i) {
                float4 xv = xp[i];
                a += xv.x * wih[i].x + xv.y * wih[i].y
                   + xv.z * wih[i].z + xv.w * wih[i].w;
            }
            const float4* hp = (const float4*)hbuf[b];
            #pragma unroll
            for (int i = 0; i < H / 4; ++i) {
                float4 hv = hp[i];
                a += hv.x * whh[i].x + hv.y * whh[i].y
                   + hv.z * whh[i].z + hv.w * whh[i].w;
            }
            acc[b] = bias + a;
        }
        #pragma unroll
        for (int b = 0; b < BQ; ++b) gbuf[b][g] = acc[b];

        // commit prefetched x into the other buffer
        if (t + 1 < T) *(float2*)&xs[cur ^ 1][bb][dd] = pxv;

        __syncthreads();

        // ---- role 2: activations + state update (thread = (w, j)) ----
        float gi = sigmoidf_(gbuf[w][j]);
        float gf = sigmoidf_(gbuf[w][H + j]);
        float gg = tanhf_  (gbuf[w][2 * H + j]);
        float go = sigmoidf_(gbuf[w][3 * H + j]);
        c = gf * c + gi * gg;
        hbuf[w][j] = go * tanhf_(c);

        __syncthreads();
        cur ^= 1;
    }

    // ---- epilogue: logits = relu(h) @ Wo^T + bo ; log_softmax over O=128 ----
    {
        float l0 = bo[j];
        float l1 = bo[j + 64];
        const float* w0 = Wo + (size_t)j * H;
        const float* w1 = Wo + (size_t)(j + 64) * H;
        #pragma unroll
        for (int k = 0; k < H; ++k) {
            float rh = fmaxf(hbuf[w][k], 0.0f);
            l0 += rh * w0[k];
            l1 += rh * w1[k];
        }
        float m = fmaxf(l0, l1);
        #pragma unroll
        for (int s = 32; s > 0; s >>= 1) m = fmaxf(m, __shfl_xor(m, s));
        float e = __expf(l0 - m) + __expf(l1 - m);
        #pragma unroll
        for (int s = 32; s > 0; s >>= 1) e += __shfl_xor(e, s);
        float lse = m + __logf(e);
        float* op = out + (size_t)(b0 + w) * O;
        op[j]      = l0 - lse;
        op[j + 64] = l1 - lse;
    }
}

extern "C" void kernel_launch(void* const* d_in, const int* in_sizes, int n_in,
                              void* d_out, int out_size, void* d_ws, size_t ws_size,
                              hipStream_t stream) {
    const float* x   = (const float*)d_in[0];
    const float* Wih = (const float*)d_in[1];
    const float* Whh = (const float*)d_in[2];
    const float* bih = (const float*)d_in[3];
    const float* bhh = (const float*)d_in[4];
    const float* Wo  = (const float*)d_in[5];
    const float* bo  = (const float*)d_in[6];
    lstm_fused<<<dim3(B / BQ), dim3(256), 0, stream>>>(
        x, Wih, Whh, bih, bhh, Wo, bo, (float*)d_out);
}

// Round 2
// 454.378 us; speedup vs baseline: 2.7550x; 2.7550x over previous
//
#include <hip/hip_runtime.h>
#include <math.h>

// Fused LSTM via bf16 MFMA. B=1024,T=256,D=128,H=64,G=256,O=128.
// 64 blocks x 256 thr; block owns BQ=16 batches for the whole scan.
// Per step: gates[16][256] = X[16][128] Wih^T + H[16][64] Whh^T via
// mfma_f32_16x16x32_bf16. Wave w owns gate cols {64q+16w+lq}: i,f,g,o for a
// cell land in one lane's acc regs -> activations + c-state fully in regs.
// Weights live as B-fragments in VGPRs (constant over t). One barrier/step.
constexpr int B = 1024, T = 256, D = 128, H = 64, O = 128;
constexpr int BQ = 16;
constexpr int XPAD = 8, HPAD = 8;   // +8 bf16 row pad: A-frag reads 2-way max

typedef __attribute__((ext_vector_type(8))) short short8;
typedef __attribute__((ext_vector_type(4))) float f32x4;

__device__ __forceinline__ unsigned short f2bf(float f) {
    union { float f; unsigned u; } v; v.f = f;
    return (unsigned short)((v.u + 0x7FFF + ((v.u >> 16) & 1)) >> 16);  // RNE
}
__device__ __forceinline__ float sigmoidf_(float x) {
    return 1.0f / (1.0f + __expf(-x));
}
__device__ __forceinline__ float tanhf_(float x) {
    float a = fabsf(x);
    float e = __expf(2.0f * a);      // e=inf -> r=1 (overflow-safe)
    float r = 1.0f - 2.0f / (e + 1.0f);
    return copysignf(r, x);
}

__global__ __launch_bounds__(256, 1)
void lstm_mfma(const float* __restrict__ x, const float* __restrict__ Wih,
               const float* __restrict__ Whh, const float* __restrict__ bih,
               const float* __restrict__ bhh, const float* __restrict__ Wo,
               const float* __restrict__ bo, float* __restrict__ out)
{
    __shared__ unsigned short xs[2][BQ][D + XPAD];  // 8704 B, x_t bf16, dbuf
    __shared__ unsigned short hs[2][BQ][H + HPAD];  // 4608 B, h_t bf16, dbuf
    __shared__ float hf[BQ][H];                     // 4 KB, final h fp32

    const int tid  = threadIdx.x;
    const int lane = tid & 63;
    const int w    = tid >> 6;     // wave 0..3 -> j-slice [16w,16w+16)
    const int lq   = lane & 15;
    const int qd   = lane >> 4;    // 0..3
    const int b0   = blockIdx.x * BQ;

    // ---- weight B-fragments: lane holds W[n][32c+8qd .. +7], n=64q+16w+lq ----
    short8 wih_f[4][4];
    short8 whh_f[4][2];
    float  bias[4];
    #pragma unroll
    for (int q = 0; q < 4; ++q) {
        const int n = 64 * q + 16 * w + lq;
        #pragma unroll
        for (int c = 0; c < 4; ++c) {
            const float* p = Wih + (size_t)n * D + 32 * c + 8 * qd;
            short8 v;
            #pragma unroll
            for (int j = 0; j < 8; ++j) v[j] = (short)f2bf(p[j]);
            wih_f[q][c] = v;
        }
        #pragma unroll
        for (int c = 0; c < 2; ++c) {
            const float* p = Whh + (size_t)n * H + 32 * c + 8 * qd;
            short8 v;
            #pragma unroll
            for (int j = 0; j < 8; ++j) v[j] = (short)f2bf(p[j]);
            whh_f[q][c] = v;
        }
        bias[q] = bih[n] + bhh[n];
    }

    // ---- stage x(0) -> xs[0]; zero hs; prefetch x(1) into regs ----
    const int ms = tid >> 4;         // batch row this thread stages
    const int ks = (tid & 15) * 8;   // 8-float chunk
    {
        const float* p = x + ((size_t)(b0 + ms) * T + 0) * D + ks;
        float4 a = *(const float4*)p, bv = *(const float4*)(p + 4);
        short8 v;
        v[0] = (short)f2bf(a.x);  v[1] = (short)f2bf(a.y);
        v[2] = (short)f2bf(a.z);  v[3] = (short)f2bf(a.w);
        v[4] = (short)f2bf(bv.x); v[5] = (short)f2bf(bv.y);
        v[6] = (short)f2bf(bv.z); v[7] = (short)f2bf(bv.w);
        *(short8*)&xs[0][ms][ks] = v;
    }
    for (int i = tid; i < 2 * BQ * (H + HPAD); i += 256)
        ((unsigned short*)hs)[i] = 0;

    float4 pa, pb;   // x(t+1) prefetch registers
    {
        const float* p = x + ((size_t)(b0 + ms) * T + 1) * D + ks;
        pa = *(const float4*)p; pb = *(const float4*)(p + 4);
    }
    __syncthreads();

    float cst[4] = {0.f, 0.f, 0.f, 0.f};  // c for (m=4qd+r, j=16w+lq)
    float hlast[4];
    int cur = 0;

    for (int t = 0; t < T; ++t) {
        const int nxt = cur ^ 1;

        // commit prefetched x(t+1) -> xs[nxt] (last read of xs[nxt] was
        // before the previous barrier -> safe)
        {
            short8 v;
            v[0] = (short)f2bf(pa.x); v[1] = (short)f2bf(pa.y);
            v[2] = (short)f2bf(pa.z); v[3] = (short)f2bf(pa.w);
            v[4] = (short)f2bf(pb.x); v[5] = (short)f2bf(pb.y);
            v[6] = (short)f2bf(pb.z); v[7] = (short)f2bf(pb.w);
            *(short8*)&xs[nxt][ms][ks] = v;
        }
        // issue x(t+2) prefetch (~1.5 steps of latency cover)
        {
            const int t2 = (t + 2 < T) ? t + 2 : T - 1;
            const float* p = x + ((size_t)(b0 + ms) * T + t2) * D + ks;
            pa = *(const float4*)p; pb = *(const float4*)(p + 4);
        }

        // A-fragments: lane = A[m=lq][k=32c+8qd .. +7]
        short8 xf[4], hfr[2];
        #pragma unroll
        for (int c = 0; c < 4; ++c)
            xf[c] = *(const short8*)&xs[cur][lq][32 * c + 8 * qd];
        #pragma unroll
        for (int c = 0; c < 2; ++c)
            hfr[c] = *(const short8*)&hs[cur][lq][32 * c + 8 * qd];

        // gates: acc[q][r] = gate q for (m=4qd+r, j=16w+lq)
        f32x4 acc[4];
        #pragma unroll
        for (int q = 0; q < 4; ++q) {
            f32x4 a = {0.f, 0.f, 0.f, 0.f};
            #pragma unroll
            for (int c = 0; c < 4; ++c)
                a = __builtin_amdgcn_mfma_f32_16x16x32_bf16(xf[c], wih_f[q][c], a, 0, 0, 0);
            #pragma unroll
            for (int c = 0; c < 2; ++c)
                a = __builtin_amdgcn_mfma_f32_16x16x32_bf16(hfr[c], whh_f[q][c], a, 0, 0, 0);
            acc[q] = a;
        }

        // activations + state update in registers; write h(t+1) bf16
        const int j = 16 * w + lq;
        #pragma unroll
        for (int r = 0; r < 4; ++r) {
            float gi = sigmoidf_(acc[0][r] + bias[0]);
            float gf = sigmoidf_(acc[1][r] + bias[1]);
            float gg = tanhf_  (acc[2][r] + bias[2]);
            float go = sigmoidf_(acc[3][r] + bias[3]);
            float c2 = gf * cst[r] + gi * gg;
            cst[r] = c2;
            float hv = go * tanhf_(c2);
            hlast[r] = hv;
            hs[nxt][4 * qd + r][j] = f2bf(hv);
        }

        __syncthreads();   // one barrier per step
        cur = nxt;
    }

    // ---- epilogue: logits = relu(h) Wo^T + bo ; log_softmax over O=128 ----
    #pragma unroll
    for (int r = 0; r < 4; ++r) hf[4 * qd + r][16 * w + lq] = hlast[r];
    __syncthreads();

    for (int it = 0; it < 4; ++it) {
        const int m = 4 * it + w;
        float l0 = bo[lane], l1 = bo[lane + 64];
        const float* w0 = Wo + (size_t)lane * H;
        const float* w1 = Wo + (size_t)(lane + 64) * H;
        #pragma unroll
        for (int k = 0; k < H; ++k) {
            float rh = fmaxf(hf[m][k], 0.0f);
            l0 += rh * w0[k];
            l1 += rh * w1[k];
        }
        float mx = fmaxf(l0, l1);
        #pragma unroll
        for (int s = 32; s > 0; s >>= 1) mx = fmaxf(mx, __shfl_xor(mx, s));
        float e = __expf(l0 - mx) + __expf(l1 - mx);
        #pragma unroll
        for (int s = 32; s > 0; s >>= 1) e += __shfl_xor(e, s);
        float lse = mx + __logf(e);
        float* op = out + (size_t)(b0 + m) * O;
        op[lane]      = l0 - lse;
        op[lane + 64] = l1 - lse;
    }
}

extern "C" void kernel_launch(void* const* d_in, const int* in_sizes, int n_in,
                              void* d_out, int out_size, void* d_ws, size_t ws_size,
                              hipStream_t stream) {
    const float* x   = (const float*)d_in[0];
    const float* Wih = (const float*)d_in[1];
    const float* Whh = (const float*)d_in[2];
    const float* bih = (const float*)d_in[3];
    const float* bhh = (const float*)d_in[4];
    const float* Wo  = (const float*)d_in[5];
    const float* bo  = (const float*)d_in[6];
    lstm_mfma<<<dim3(B / BQ), dim3(256), 0, stream>>>(
        x, Wih, Whh, bih, bhh, Wo, bo, (float*)d_out);
}